// Round 4
// baseline (189.090 us; speedup 1.0000x reference)
//
#include <hip/hip_runtime.h>

typedef __attribute__((ext_vector_type(8))) short short8;
typedef __attribute__((ext_vector_type(2))) float float2_t;
typedef __attribute__((ext_vector_type(4))) float float4_t;
typedef __attribute__((ext_vector_type(4))) int int4_t;
typedef __attribute__((ext_vector_type(2))) unsigned uint2_t;

#define CH_STRIDE 4096        // 64*64 spatial per channel
#define IMG_STRIDE 524288     // 128 channels * 4096
#define HW 4096
#define V520 520              // Vt row stride (shorts); 1040B rows keep 16B align

// float -> bf16 bits, round-to-nearest-even (finite inputs only)
static __device__ __forceinline__ short f2b(float x) {
    unsigned u = __builtin_bit_cast(unsigned, x);
    u = (u + 0x7fffu + ((u >> 16) & 1u)) >> 16;
    return (short)u;
}
static __device__ __forceinline__ float bitsf(unsigned u) { return __builtin_bit_cast(float, u); }
static __device__ __forceinline__ unsigned bitsu(float f) { return __builtin_bit_cast(unsigned, f); }

// Fused CSWin block: flash attention (S^T = K*Q^T, permlane P-exchange,
// O^T = V^T*P^T) + depthwise 3x3 conv rpe from LDS-resident V, one launch.
//
// R4: occupancy via grid split. R1-R3 showed every in-loop change (barrier
// removal, load hiding, bpermute->permlane, bank conflicts -73%) is ~neutral:
// wall ~4x any pipe-sum -> latency-bound with only 16/32 waves resident.
// Resources allow 3 blocks/CU (VGPR 84 -> 6 waves/SIMD; LDS 43.5KB x3 =
// 130.5KB <= 160KB) but grid 512 = 2/CU caps residency. Split each
// window-head's 512 q-rows across TWO blocks (grid 1024, bit 6 = half):
// qt=2 drops ~25 regs of state vs qt=4's 84 -> natural VGPR well under the
// 85 needed for 6 waves/SIMD -> 3 blocks/CU resident (+50% waves).
// NO launch_bounds min-waves arg: R1's (512,6) cap on the qt=4 state forced
// spills (246us + replay divergence). Natural allocation only.
// #pragma unroll 2 on the chunk loop: resolves ch&1 buffer parity at compile
// time without 8x code bloat (I-cache hedge).
// Cost: K/V read by both halves (+33MB fetch, HBM at 15% has headroom);
// both halves stage the full Vt (needed for attention keys + conv halo).
// Correctness of split (first-run-verified in R1): softmax is per-q-row
// (wave-local), conv h-range half*32..+31 == this block's own O rows ->
// RMW stays block-local; halves/heads/windows touch disjoint out lines.
__global__ __launch_bounds__(512) void cswin_fused(
    const float* __restrict__ temp, const float* __restrict__ cw,
    const float* __restrict__ cb, float* __restrict__ out)
{
    __shared__ short Kc[2][64 * 40];   // [buf][key][d] pad-40, double-buffered
    __shared__ short Vt[32 * V520];    // [d][l] full 512-key window, persistent

    int bx = blockIdx.x;
    int nw   = bx >> 7;        // window column 0..7 (high bits: XCD L2 locality)
    int half = (bx >> 6) & 1;  // q-row half 0..1 (same XCD as sibling half)
    int b    = (bx >> 2) & 15; // batch
    int n    = bx & 3;         // head

    int t    = threadIdx.x;
    int wv   = t >> 6;         // wave 0..7
    int lane = t & 63;
    int mr   = lane & 15;
    int q    = lane >> 4;

    const float* tq = temp + (size_t)b * 3 * IMG_STRIDE + (size_t)(n * 32) * CH_STRIDE + nw * 8;
    const float* tk = tq + IMG_STRIDE;
    const float* tv = tk + IMG_STRIDE;

    int row0 = half * 256 + wv * 32;   // this wave's 32 q-rows
    const float qscale = 0.2550348889072310f;   // (1/sqrt(32)) * log2(e)

    // Q fragments (B-operand): lane holds Q[row0+qt*16+mr][q*8+j] * qscale
    short8 Qf[2];
    #pragma unroll
    for (int qt = 0; qt < 2; ++qt) {
        int l = row0 + qt * 16 + mr;
        int sp = (l >> 3) * 64 + (l & 7);
        short8 f;
        #pragma unroll
        for (int j = 0; j < 8; ++j)
            f[j] = f2b(tq[(q * 8 + j) * CH_STRIDE + sp] * qscale);
        Qf[qt] = f;
    }

    float4_t zero4 = {0.f, 0.f, 0.f, 0.f};
    float4_t acc[2][2];
    #pragma unroll
    for (int dt = 0; dt < 2; ++dt)
        #pragma unroll
        for (int qt = 0; qt < 2; ++qt)
            acc[dt][qt] = zero4;
    float lsum[2] = {0.f, 0.f};

    // loader mapping: 512 threads = 32 d x 16 key-slots; thread (ld,seg)
    // handles keys seg+16i (i=0..3) -> low-conflict b16 Kc stores.
    // Both halves stage the FULL 512-key window (attention + conv halo).
    int ld  = t >> 4;          // channel d 0..31
    int seg = t & 15;
    const float* tkld = tk + (size_t)ld * CH_STRIDE;
    const float* tvld = tv + (size_t)ld * CH_STRIDE;

    float kx[4], vx[4];
    #pragma unroll
    for (int i = 0; i < 4; ++i) {      // prefetch chunk 0
        int lb = seg + 16 * i;
        int sp = (lb >> 3) * 64 + (lb & 7);
        kx[i] = tkld[sp]; vx[i] = tvld[sp];
    }
    {   // prologue: stage chunk 0 into Kc[0] / Vt[0..63]
        #pragma unroll
        for (int i = 0; i < 4; ++i) {
            int kl = seg + 16 * i;
            Kc[0][kl * 40 + ld] = f2b(kx[i]);
            Vt[ld * V520 + kl]  = f2b(vx[i]);
        }
    }

    #pragma unroll 2
    for (int ch = 0; ch < 8; ++ch) {
        if (ch < 7) {          // issue next chunk's loads before the barrier
            #pragma unroll
            for (int i = 0; i < 4; ++i) {
                int lb = (ch + 1) * 64 + seg + 16 * i;
                int sp = (lb >> 3) * 64 + (lb & 7);
                kx[i] = tkld[sp]; vx[i] = tvld[sp];
            }
        }
        __syncthreads();       // publishes chunk ch's Kc/Vt writes
        const short* Kr = Kc[ch & 1];

        #pragma unroll
        for (int g = 0; g < 2; ++g) {
            // S^T tiles: D[m=key][n=qrow], keys g*32..g*32+31 (local to chunk)
            short8 KaA = *reinterpret_cast<const short8*>(&Kr[((2 * g) * 16 + mr) * 40 + q * 8]);
            short8 KaB = *reinterpret_cast<const short8*>(&Kr[((2 * g + 1) * 16 + mr) * 40 + q * 8]);
            unsigned pa0[2], pa1[2], pb0[2], pb1[2];
            #pragma unroll
            for (int qt = 0; qt < 2; ++qt) {
                float4_t sA = __builtin_amdgcn_mfma_f32_16x16x32_bf16(KaA, Qf[qt], zero4, 0, 0, 0);
                float4_t sB = __builtin_amdgcn_mfma_f32_16x16x32_bf16(KaB, Qf[qt], zero4, 0, 0, 0);
                float eA0 = __builtin_amdgcn_exp2f(sA.x), eA1 = __builtin_amdgcn_exp2f(sA.y);
                float eA2 = __builtin_amdgcn_exp2f(sA.z), eA3 = __builtin_amdgcn_exp2f(sA.w);
                float eB0 = __builtin_amdgcn_exp2f(sB.x), eB1 = __builtin_amdgcn_exp2f(sB.y);
                float eB2 = __builtin_amdgcn_exp2f(sB.z), eB3 = __builtin_amdgcn_exp2f(sB.w);
                lsum[qt] += ((eA0 + eA1) + (eA2 + eA3)) + ((eB0 + eB1) + (eB2 + eB3));
                // pack pairs (truncation) with one v_perm each: [lo16=e_even, hi16=e_odd]
                pa0[qt] = __builtin_amdgcn_perm(bitsu(eA1), bitsu(eA0), 0x07060302u);
                pa1[qt] = __builtin_amdgcn_perm(bitsu(eA3), bitsu(eA2), 0x07060302u);
                pb0[qt] = __builtin_amdgcn_perm(bitsu(eB1), bitsu(eB0), 0x07060302u);
                pb1[qt] = __builtin_amdgcn_perm(bitsu(eB3), bitsu(eB2), 0x07060302u);
            }
            // V^T A-fragments for this 32-key group
            int base = ch * 64 + g * 32 + q * 8;
            short8 Va0 = *reinterpret_cast<const short8*>(&Vt[mr * V520 + base]);
            short8 Va1 = *reinterpret_cast<const short8*>(&Vt[(16 + mr) * V520 + base]);
            #pragma unroll
            for (int qt = 0; qt < 2; ++qt) {
                // C-layout P (keys q*4+r) -> B-operand (keys q*8+j) in-register:
                // word w of dest lane (q,mr) comes from lane (q&1)*32+(w>>1)*16+mr
                // of pa (q<2) / pb (q>=2). Two swap stages produce two words each.
                uint2_t re = __builtin_amdgcn_permlane32_swap(pa0[qt], pb0[qt], 0, 0);
                uint2_t we = __builtin_amdgcn_permlane16_swap(re.x, re.y, 0, 0);   // {w0, w2}
                uint2_t ro = __builtin_amdgcn_permlane32_swap(pa1[qt], pb1[qt], 0, 0);
                uint2_t wo = __builtin_amdgcn_permlane16_swap(ro.x, ro.y, 0, 0);   // {w1, w3}
                int4_t pi = { (int)we.x, (int)wo.x, (int)we.y, (int)wo.y };
                short8 Pb = __builtin_bit_cast(short8, pi);
                acc[0][qt] = __builtin_amdgcn_mfma_f32_16x16x32_bf16(Va0, Pb, acc[0][qt], 0, 0, 0);
                acc[1][qt] = __builtin_amdgcn_mfma_f32_16x16x32_bf16(Va1, Pb, acc[1][qt], 0, 0, 0);
            }
        }

        if (ch < 7) {          // stage chunk ch+1 (loads hidden under compute)
            short* Kw = Kc[(ch + 1) & 1];
            #pragma unroll
            for (int i = 0; i < 4; ++i) {
                int kl = seg + 16 * i;
                Kw[kl * 40 + ld] = f2b(kx[i]);
                Vt[ld * V520 + (ch + 1) * 64 + kl] = f2b(vx[i]);
            }
        }
    }

    // softmax denominators: reduce across quads, invert
    float inv[2];
    #pragma unroll
    for (int qt = 0; qt < 2; ++qt) {
        float v = lsum[qt];
        v += __shfl_xor(v, 16);
        v += __shfl_xor(v, 32);
        inv[qt] = 1.0f / v;
    }

    // O store: lane holds O[qrow=row0+qt*16+mr][c = n*32 + dt*16 + q*4 + r]
    float* outb = out + (size_t)b * HW * 128 + nw * 8 * 128 + n * 32;
    #pragma unroll
    for (int qt = 0; qt < 2; ++qt) {
        int l = row0 + qt * 16 + mr;
        size_t basep = (size_t)((l >> 3) * 64 + (l & 7)) * 128;
        #pragma unroll
        for (int dt = 0; dt < 2; ++dt) {
            float4_t o = acc[dt][qt] * inv[qt];
            *reinterpret_cast<float4_t*>(outb + basep + dt * 16 + q * 4) = o;
        }
    }

    __syncthreads();   // O-stores visible block-wide; Vt complete since last barrier

    // ---- depthwise 3x3 conv + bias (window-local SAME pad) from LDS V, RMW out
    // This block covers only its own half-window rows: h = half*32..+31
    // (== this block's own O rows -> RMW stays block-local). Vt holds the
    // FULL window so h-1/h+1 halo rows are available on both halves.
    // 512 threads = 32 h-rows x 16 channel-pairs.
    int c2 = (t & 15) * 2;             // relative channel 0,2,..,30
    int h  = half * 32 + (t >> 4);     // window-global row
    float2_t outv[8];
    #pragma unroll
    for (int cc = 0; cc < 2; ++cc) {
        int c = c2 + cc;
        float w9[9];
        #pragma unroll
        for (int i = 0; i < 9; ++i) w9[i] = cw[(n * 32 + c) * 9 + i];
        float bias = cb[n * 32 + c];
        float rv[3][8];
        #pragma unroll
        for (int rr = 0; rr < 3; ++rr) {
            int hh = h - 1 + rr;
            if (hh >= 0 && hh < 64) {
                short8 u = *reinterpret_cast<const short8*>(&Vt[c * V520 + hh * 8]);
                #pragma unroll
                for (int j = 0; j < 8; ++j)
                    rv[rr][j] = bitsf(((unsigned)(unsigned short)u[j]) << 16);
            } else {
                #pragma unroll
                for (int j = 0; j < 8; ++j) rv[rr][j] = 0.f;
            }
        }
        #pragma unroll
        for (int w = 0; w < 8; ++w) {
            float o = bias;
            #pragma unroll
            for (int rr = 0; rr < 3; ++rr) {
                if (w > 0) o += rv[rr][w - 1] * w9[rr * 3 + 0];
                o += rv[rr][w] * w9[rr * 3 + 1];
                if (w < 7) o += rv[rr][w + 1] * w9[rr * 3 + 2];
            }
            outv[w][cc] = o;
        }
    }
    #pragma unroll
    for (int w = 0; w < 8; ++w) {
        size_t off = (size_t)h * 8192 + w * 128 + c2;
        float2_t cur = *reinterpret_cast<const float2_t*>(outb + off);
        cur += outv[w];
        *reinterpret_cast<float2_t*>(outb + off) = cur;
    }
}

extern "C" void kernel_launch(void* const* d_in, const int* in_sizes, int n_in,
                              void* d_out, int out_size, void* d_ws, size_t ws_size,
                              hipStream_t stream) {
    const float* temp = (const float*)d_in[0];
    const float* cw   = (const float*)d_in[1];
    const float* cb   = (const float*)d_in[2];
    float* out = (float*)d_out;
    hipLaunchKernelGGL(cswin_fused, dim3(1024), dim3(512), 0, stream, temp, cw, cb, out);
}

// Round 5
// 186.355 us; speedup vs baseline: 1.0147x; 1.0147x over previous
//
#include <hip/hip_runtime.h>

typedef __attribute__((ext_vector_type(8))) short short8;
typedef __attribute__((ext_vector_type(2))) float float2_t;
typedef __attribute__((ext_vector_type(4))) float float4_t;
typedef __attribute__((ext_vector_type(4))) int int4_t;
typedef __attribute__((ext_vector_type(2))) unsigned uint2_t;

#define CH_STRIDE 4096        // 64*64 spatial per channel
#define IMG_STRIDE 524288     // 128 channels * 4096
#define HW 4096
#define V520 520              // Vt row stride (shorts); 1040B rows keep 16B align

// float -> bf16 bits, round-to-nearest-even (finite inputs only)
static __device__ __forceinline__ short f2b(float x) {
    unsigned u = __builtin_bit_cast(unsigned, x);
    u = (u + 0x7fffu + ((u >> 16) & 1u)) >> 16;
    return (short)u;
}
static __device__ __forceinline__ float bitsf(unsigned u) { return __builtin_bit_cast(float, u); }
static __device__ __forceinline__ unsigned bitsu(float f) { return __builtin_bit_cast(unsigned, f); }

// Fused CSWin block: flash attention (S^T = K*Q^T, permlane P-exchange,
// O^T = V^T*P^T) + depthwise 3x3 conv rpe from LDS-resident V, one launch.
//
// R5: max occupancy. R4 (half-split, grid 1024, VGPR 56, 3 blocks/CU = 24
// waves) showed throughput/work scaled ~1.35x with 1.5x waves -> still
// latency-bound; occupancy is the working axis. VGPR 56 <= 64 already allows
// 8 waves/SIMD; grid 1024 = exactly 4 blocks/CU of work; the ONLY cap at 3
// blocks/CU was LDS (43.52KB x4 > 160KB). Single-buffer Kc (R2 proved the
// barrier structure is worth ~0%) -> 38.4KB x4 = 153.6KB <= 160KB ->
// 4 blocks/CU = 32 waves/CU resident. Register prefetch stays 2-deep
// (loads for ch+2 issued at stage(ch+1), in flight across compute(ch+1)).
// #pragma unroll 1 on the chunk loop keeps code footprint small.
// NO launch_bounds min-waves arg (R1: caps below natural allocation spill).
// VGPR MUST stay <= 64 for 4-block residency — verify in counters.
__global__ __launch_bounds__(512) void cswin_fused(
    const float* __restrict__ temp, const float* __restrict__ cw,
    const float* __restrict__ cb, float* __restrict__ out)
{
    __shared__ short Kc[64 * 40];      // [key][d] pad-40, single buffer
    __shared__ short Vt[32 * V520];    // [d][l] full 512-key window, persistent

    int bx = blockIdx.x;
    int nw   = bx >> 7;        // window column 0..7 (high bits: XCD L2 locality)
    int half = (bx >> 6) & 1;  // q-row half 0..1 (same XCD as sibling half)
    int b    = (bx >> 2) & 15; // batch
    int n    = bx & 3;         // head

    int t    = threadIdx.x;
    int wv   = t >> 6;         // wave 0..7
    int lane = t & 63;
    int mr   = lane & 15;
    int q    = lane >> 4;

    const float* tq = temp + (size_t)b * 3 * IMG_STRIDE + (size_t)(n * 32) * CH_STRIDE + nw * 8;
    const float* tk = tq + IMG_STRIDE;
    const float* tv = tk + IMG_STRIDE;

    int row0 = half * 256 + wv * 32;   // this wave's 32 q-rows
    const float qscale = 0.2550348889072310f;   // (1/sqrt(32)) * log2(e)

    // Q fragments (B-operand): lane holds Q[row0+qt*16+mr][q*8+j] * qscale
    short8 Qf[2];
    #pragma unroll
    for (int qt = 0; qt < 2; ++qt) {
        int l = row0 + qt * 16 + mr;
        int sp = (l >> 3) * 64 + (l & 7);
        short8 f;
        #pragma unroll
        for (int j = 0; j < 8; ++j)
            f[j] = f2b(tq[(q * 8 + j) * CH_STRIDE + sp] * qscale);
        Qf[qt] = f;
    }

    float4_t zero4 = {0.f, 0.f, 0.f, 0.f};
    float4_t acc[2][2];
    #pragma unroll
    for (int dt = 0; dt < 2; ++dt)
        #pragma unroll
        for (int qt = 0; qt < 2; ++qt)
            acc[dt][qt] = zero4;
    float lsum[2] = {0.f, 0.f};

    // loader mapping: 512 threads = 32 d x 16 key-slots; thread (ld,seg)
    // handles keys seg+16i (i=0..3) -> low-conflict b16 Kc stores.
    // Both halves stage the FULL 512-key window (attention + conv halo).
    int ld  = t >> 4;          // channel d 0..31
    int seg = t & 15;
    const float* tkld = tk + (size_t)ld * CH_STRIDE;
    const float* tvld = tv + (size_t)ld * CH_STRIDE;

    float kx[4], vx[4];
    #pragma unroll
    for (int i = 0; i < 4; ++i) {      // load chunk 0
        int lb = seg + 16 * i;
        int sp = (lb >> 3) * 64 + (lb & 7);
        kx[i] = tkld[sp]; vx[i] = tvld[sp];
    }
    {   // prologue: stage chunk 0 into Kc / Vt[0..63]
        #pragma unroll
        for (int i = 0; i < 4; ++i) {
            int kl = seg + 16 * i;
            Kc[kl * 40 + ld] = f2b(kx[i]);
            Vt[ld * V520 + kl]  = f2b(vx[i]);
        }
    }
    #pragma unroll
    for (int i = 0; i < 4; ++i) {      // issue chunk-1 loads (fly over compute 0)
        int lb = 64 + seg + 16 * i;
        int sp = (lb >> 3) * 64 + (lb & 7);
        kx[i] = tkld[sp]; vx[i] = tvld[sp];
    }

    #pragma unroll 1
    for (int ch = 0; ch < 8; ++ch) {
        __syncthreads();       // publishes chunk ch's Kc/Vt writes

        #pragma unroll
        for (int g = 0; g < 2; ++g) {
            // S^T tiles: D[m=key][n=qrow], keys g*32..g*32+31 (local to chunk)
            short8 KaA = *reinterpret_cast<const short8*>(&Kc[((2 * g) * 16 + mr) * 40 + q * 8]);
            short8 KaB = *reinterpret_cast<const short8*>(&Kc[((2 * g + 1) * 16 + mr) * 40 + q * 8]);
            unsigned pa0[2], pa1[2], pb0[2], pb1[2];
            #pragma unroll
            for (int qt = 0; qt < 2; ++qt) {
                float4_t sA = __builtin_amdgcn_mfma_f32_16x16x32_bf16(KaA, Qf[qt], zero4, 0, 0, 0);
                float4_t sB = __builtin_amdgcn_mfma_f32_16x16x32_bf16(KaB, Qf[qt], zero4, 0, 0, 0);
                float eA0 = __builtin_amdgcn_exp2f(sA.x), eA1 = __builtin_amdgcn_exp2f(sA.y);
                float eA2 = __builtin_amdgcn_exp2f(sA.z), eA3 = __builtin_amdgcn_exp2f(sA.w);
                float eB0 = __builtin_amdgcn_exp2f(sB.x), eB1 = __builtin_amdgcn_exp2f(sB.y);
                float eB2 = __builtin_amdgcn_exp2f(sB.z), eB3 = __builtin_amdgcn_exp2f(sB.w);
                lsum[qt] += ((eA0 + eA1) + (eA2 + eA3)) + ((eB0 + eB1) + (eB2 + eB3));
                // pack pairs (truncation) with one v_perm each: [lo16=e_even, hi16=e_odd]
                pa0[qt] = __builtin_amdgcn_perm(bitsu(eA1), bitsu(eA0), 0x07060302u);
                pa1[qt] = __builtin_amdgcn_perm(bitsu(eA3), bitsu(eA2), 0x07060302u);
                pb0[qt] = __builtin_amdgcn_perm(bitsu(eB1), bitsu(eB0), 0x07060302u);
                pb1[qt] = __builtin_amdgcn_perm(bitsu(eB3), bitsu(eB2), 0x07060302u);
            }
            // V^T A-fragments for this 32-key group
            int base = ch * 64 + g * 32 + q * 8;
            short8 Va0 = *reinterpret_cast<const short8*>(&Vt[mr * V520 + base]);
            short8 Va1 = *reinterpret_cast<const short8*>(&Vt[(16 + mr) * V520 + base]);
            #pragma unroll
            for (int qt = 0; qt < 2; ++qt) {
                // C-layout P (keys q*4+r) -> B-operand (keys q*8+j) in-register:
                // word w of dest lane (q,mr) comes from lane (q&1)*32+(w>>1)*16+mr
                // of pa (q<2) / pb (q>=2). Two swap stages produce two words each.
                uint2_t re = __builtin_amdgcn_permlane32_swap(pa0[qt], pb0[qt], 0, 0);
                uint2_t we = __builtin_amdgcn_permlane16_swap(re.x, re.y, 0, 0);   // {w0, w2}
                uint2_t ro = __builtin_amdgcn_permlane32_swap(pa1[qt], pb1[qt], 0, 0);
                uint2_t wo = __builtin_amdgcn_permlane16_swap(ro.x, ro.y, 0, 0);   // {w1, w3}
                int4_t pi = { (int)we.x, (int)wo.x, (int)we.y, (int)wo.y };
                short8 Pb = __builtin_bit_cast(short8, pi);
                acc[0][qt] = __builtin_amdgcn_mfma_f32_16x16x32_bf16(Va0, Pb, acc[0][qt], 0, 0, 0);
                acc[1][qt] = __builtin_amdgcn_mfma_f32_16x16x32_bf16(Va1, Pb, acc[1][qt], 0, 0, 0);
            }
        }

        if (ch < 7) {
            __syncthreads();   // all waves done reading Kc for chunk ch
            // stage chunk ch+1 (loads issued one chunk ago, latency hidden)
            #pragma unroll
            for (int i = 0; i < 4; ++i) {
                int kl = seg + 16 * i;
                Kc[kl * 40 + ld] = f2b(kx[i]);
                Vt[ld * V520 + (ch + 1) * 64 + kl] = f2b(vx[i]);
            }
            if (ch < 6) {      // issue chunk ch+2 loads (fly over compute ch+1)
                #pragma unroll
                for (int i = 0; i < 4; ++i) {
                    int lb = (ch + 2) * 64 + seg + 16 * i;
                    int sp = (lb >> 3) * 64 + (lb & 7);
                    kx[i] = tkld[sp]; vx[i] = tvld[sp];
                }
            }
        }
    }

    // softmax denominators: reduce across quads, invert
    float inv[2];
    #pragma unroll
    for (int qt = 0; qt < 2; ++qt) {
        float v = lsum[qt];
        v += __shfl_xor(v, 16);
        v += __shfl_xor(v, 32);
        inv[qt] = 1.0f / v;
    }

    // O store: lane holds O[qrow=row0+qt*16+mr][c = n*32 + dt*16 + q*4 + r]
    float* outb = out + (size_t)b * HW * 128 + nw * 8 * 128 + n * 32;
    #pragma unroll
    for (int qt = 0; qt < 2; ++qt) {
        int l = row0 + qt * 16 + mr;
        size_t basep = (size_t)((l >> 3) * 64 + (l & 7)) * 128;
        #pragma unroll
        for (int dt = 0; dt < 2; ++dt) {
            float4_t o = acc[dt][qt] * inv[qt];
            *reinterpret_cast<float4_t*>(outb + basep + dt * 16 + q * 4) = o;
        }
    }

    __syncthreads();   // O-stores visible block-wide; Vt complete since last barrier

    // ---- depthwise 3x3 conv + bias (window-local SAME pad) from LDS V, RMW out
    // This block covers only its own half-window rows: h = half*32..+31
    // (== this block's own O rows -> RMW stays block-local). Vt holds the
    // FULL window so h-1/h+1 halo rows are available on both halves.
    // 512 threads = 32 h-rows x 16 channel-pairs.
    int c2 = (t & 15) * 2;             // relative channel 0,2,..,30
    int h  = half * 32 + (t >> 4);     // window-global row
    float2_t outv[8];
    #pragma unroll
    for (int cc = 0; cc < 2; ++cc) {
        int c = c2 + cc;
        float w9[9];
        #pragma unroll
        for (int i = 0; i < 9; ++i) w9[i] = cw[(n * 32 + c) * 9 + i];
        float bias = cb[n * 32 + c];
        float rv[3][8];
        #pragma unroll
        for (int rr = 0; rr < 3; ++rr) {
            int hh = h - 1 + rr;
            if (hh >= 0 && hh < 64) {
                short8 u = *reinterpret_cast<const short8*>(&Vt[c * V520 + hh * 8]);
                #pragma unroll
                for (int j = 0; j < 8; ++j)
                    rv[rr][j] = bitsf(((unsigned)(unsigned short)u[j]) << 16);
            } else {
                #pragma unroll
                for (int j = 0; j < 8; ++j) rv[rr][j] = 0.f;
            }
        }
        #pragma unroll
        for (int w = 0; w < 8; ++w) {
            float o = bias;
            #pragma unroll
            for (int rr = 0; rr < 3; ++rr) {
                if (w > 0) o += rv[rr][w - 1] * w9[rr * 3 + 0];
                o += rv[rr][w] * w9[rr * 3 + 1];
                if (w < 7) o += rv[rr][w + 1] * w9[rr * 3 + 2];
            }
            outv[w][cc] = o;
        }
    }
    #pragma unroll
    for (int w = 0; w < 8; ++w) {
        size_t off = (size_t)h * 8192 + w * 128 + c2;
        float2_t cur = *reinterpret_cast<const float2_t*>(outb + off);
        cur += outv[w];
        *reinterpret_cast<float2_t*>(outb + off) = cur;
    }
}

extern "C" void kernel_launch(void* const* d_in, const int* in_sizes, int n_in,
                              void* d_out, int out_size, void* d_ws, size_t ws_size,
                              hipStream_t stream) {
    const float* temp = (const float*)d_in[0];
    const float* cw   = (const float*)d_in[1];
    const float* cb   = (const float*)d_in[2];
    float* out = (float*)d_out;
    hipLaunchKernelGGL(cswin_fused, dim3(1024), dim3(512), 0, stream, temp, cw, cb, out);
}